// Round 1
// baseline (199.846 us; speedup 1.0000x reference)
//
#include <hip/hip_runtime.h>

// INT8-style BERT embeddings + approx LayerNorm, MI355X (gfx950).
// Layout: H=768 = 3 groups/lane * 64 lanes * 4 ints (int4 vector loads).
// One wave (64 lanes) per token -> shuffle reductions only, no LDS/barriers.

constexpr int H_DIM = 768;
constexpr int TPB = 256;          // 4 waves
constexpr int TOK_PER_BLK = 4;    // one token per wave

__global__ __launch_bounds__(TPB) void bert_emb_kernel(
    const int* __restrict__ input_ids,
    const int* __restrict__ token_type_ids,
    const int* __restrict__ word_table,
    const float* __restrict__ word_scale,
    const int* __restrict__ pos_table,
    const float* __restrict__ pos_scale,
    const int* __restrict__ type_table,
    const float* __restrict__ type_scale,
    const float* __restrict__ ln_w,
    const float* __restrict__ ln_b,
    float* __restrict__ out,
    int n_tokens, int S)
{
    const int wave = threadIdx.x >> 6;
    const int lane = threadIdx.x & 63;
    const int token = blockIdx.x * TOK_PER_BLK + wave;
    if (token >= n_tokens) return;

    const int s   = token % S;              // position id
    const int wid = input_ids[token];
    const int tt  = token_type_ids[token];

    const float ws = word_scale[0];
    const float ps = pos_scale[0];
    const float ts = type_scale[0];

    const int4* __restrict__ wrow = (const int4*)(word_table + (long long)wid * H_DIM);
    const int4* __restrict__ prow = (const int4*)(pos_table  + (long long)s   * H_DIM);
    const int4* __restrict__ trow = (const int4*)(type_table + (long long)tt  * H_DIM);

    // gather + dequant + add: 12 elements/lane held in registers
    float e[3][4];
    float sum = 0.f;
#pragma unroll
    for (int j = 0; j < 3; ++j) {
        const int g = j * 64 + lane;
        const int4 w4 = wrow[g];
        const int4 p4 = prow[g];
        const int4 t4 = trow[g];
        e[j][0] = (float)w4.x * ws + (float)p4.x * ps + (float)t4.x * ts;
        e[j][1] = (float)w4.y * ws + (float)p4.y * ps + (float)t4.y * ts;
        e[j][2] = (float)w4.z * ws + (float)p4.z * ps + (float)t4.z * ts;
        e[j][3] = (float)w4.w * ws + (float)p4.w * ps + (float)t4.w * ts;
        sum += e[j][0] + e[j][1] + e[j][2] + e[j][3];
    }

    // wave-wide butterfly reduction for mean (all lanes end with the total)
#pragma unroll
    for (int off = 1; off < 64; off <<= 1) sum += __shfl_xor(sum, off);
    const float mean = sum * (1.0f / (float)H_DIM);

    // second pass: centered sum of squares (emb is in registers)
    float sq = 0.f;
#pragma unroll
    for (int j = 0; j < 3; ++j) {
#pragma unroll
        for (int k = 0; k < 4; ++k) {
            const float d = e[j][k] - mean;
            sq += d * d;
        }
    }
#pragma unroll
    for (int off = 1; off < 64; off <<= 1) sq += __shfl_xor(sq, off);
    const float var = sq * (1.0f / (float)H_DIM);

    // Newton-Raphson sqrt, faithful to the reference (8 iters, 1e-9 guard)
    float x = (var > 1.0f) ? var * 0.5f : 1.0f;
#pragma unroll
    for (int i = 0; i < 8; ++i) x = 0.5f * (x + var / (x + 1e-9f));
    const float inv = 1.0f / (x + 1e-12f);

    // epilogue: normalize, affine, coalesced float4 stores
    float4* __restrict__ orow = (float4*)(out + (long long)token * H_DIM);
    const float4* __restrict__ lwv = (const float4*)ln_w;
    const float4* __restrict__ lbv = (const float4*)ln_b;
#pragma unroll
    for (int j = 0; j < 3; ++j) {
        const int g = j * 64 + lane;
        const float4 lw = lwv[g];
        const float4 lb = lbv[g];
        float4 o;
        o.x = lw.x * ((e[j][0] - mean) * inv) + lb.x;
        o.y = lw.y * ((e[j][1] - mean) * inv) + lb.y;
        o.z = lw.z * ((e[j][2] - mean) * inv) + lb.z;
        o.w = lw.w * ((e[j][3] - mean) * inv) + lb.w;
        orow[g] = o;
    }
}

extern "C" void kernel_launch(void* const* d_in, const int* in_sizes, int n_in,
                              void* d_out, int out_size, void* d_ws, size_t ws_size,
                              hipStream_t stream) {
    const int*   input_ids      = (const int*)d_in[0];
    const int*   token_type_ids = (const int*)d_in[1];
    const int*   word_table     = (const int*)d_in[2];
    const float* word_scale     = (const float*)d_in[3];
    const int*   pos_table      = (const int*)d_in[4];
    const float* pos_scale      = (const float*)d_in[5];
    const int*   type_table     = (const int*)d_in[6];
    const float* type_scale     = (const float*)d_in[7];
    const float* ln_w           = (const float*)d_in[8];
    const float* ln_b           = (const float*)d_in[9];
    float* out = (float*)d_out;

    const int n_tokens = in_sizes[0];        // B*S
    const int S = in_sizes[4] / H_DIM;       // pos_table rows

    const int blocks = (n_tokens + TOK_PER_BLK - 1) / TOK_PER_BLK;
    bert_emb_kernel<<<blocks, TPB, 0, stream>>>(
        input_ids, token_type_ids, word_table, word_scale,
        pos_table, pos_scale, type_table, type_scale,
        ln_w, ln_b, out, n_tokens, S);
}